// Round 8
// baseline (244.233 us; speedup 1.0000x reference)
//
#include <hip/hip_runtime.h>

// pol[g] = sum_{i in g} (q_i - mean(q)) * r_i = (sum_g q r) - mean * (sum_g r)
// Round 8: streaming-shaped pol_main — 8192 blocks x 256 thr, 4 nodes/thread,
// 4 vector loads/thread, low VGPR -> full occupancy + fast block churn (the
// copy/RMSNorm microbench shape). Wave (256 nodes) purity check: pure waves do
// one 7-value butterfly; mixed waves do A/B compare-select (proven R5 logic).
// split_kernel precomputes per-tile {i0,i1,split}; finalize (proven) computes
// mean from tile qsums and gathers per-graph partials via binary search.

#define N_NODES     8388608
#define NUM_GRAPHS  1024
#define BLK         256
#define TILE_NODES  1024
#define NT          (N_NODES / TILE_NODES)          // 8192 tiles
#define NSLOT       4

// ws layout (float offsets)
#define IBASE_OFF   16                               // int ibase[NT]
#define SPLIT_OFF   (IBASE_OFF + NT)                 // int4 split[NT] (16B aligned)
#define REC_OFF     (SPLIT_OFF + 4 * NT)             // rec[NT][32]: [0]=qsum, [8..31]=slots
#define REC_STRIDE  32
#define EXTRA_OFF   (REC_OFF + NT * REC_STRIDE)      // extra[NUM_GRAPHS][6]
#define WS_FLOATS   (EXTRA_OFF + NUM_GRAPHS * 6)     // ~309K floats = 1.24 MB

__global__ __launch_bounds__(BLK) void split_kernel(const int* __restrict__ batch,
                                                    float* __restrict__ ws) {
    int b = blockIdx.x * BLK + threadIdx.x;          // tile id, 0..NT-1
    if (b >= NT) return;
    if (b < 2048) {                                  // zero extra[]: 6144 floats
        float* extra = ws + EXTRA_OFF;
        extra[b * 3 + 0] = 0.f; extra[b * 3 + 1] = 0.f; extra[b * 3 + 2] = 0.f;
    }
    const int s = b * TILE_NODES;
    const int e = s + TILE_NODES;
    int i0 = batch[s];
    int i1 = batch[e - 1];
    int split = e;
    if (i1 != i0) {                                  // first idx in (s,e) with batch > i0
        int lo = s + 1, hi = e - 1;
        while (lo < hi) {
            int mid = (lo + hi) >> 1;
            if (batch[mid] > i0) hi = mid; else lo = mid + 1;
        }
        split = lo;
    }
    ((int4*)(ws + SPLIT_OFF))[b] = make_int4(i0, i1, split, 0);
    ((int*)(ws + IBASE_OFF))[b] = i0;
}

__device__ __forceinline__ void flush_seg(int id, int base,
                                          float qx, float qy, float qz,
                                          float rx, float ry, float rz,
                                          float* sslot, float* extra) {
    int s = id - base;
    if (s >= 0 && s < NSLOT) {
        atomicAdd(&sslot[s * 6 + 0], qx); atomicAdd(&sslot[s * 6 + 1], qy);
        atomicAdd(&sslot[s * 6 + 2], qz); atomicAdd(&sslot[s * 6 + 3], rx);
        atomicAdd(&sslot[s * 6 + 4], ry); atomicAdd(&sslot[s * 6 + 5], rz);
    } else {  // impossible for this input; correct fallback
        atomicAdd(&extra[id * 6 + 0], qx); atomicAdd(&extra[id * 6 + 1], qy);
        atomicAdd(&extra[id * 6 + 2], qz); atomicAdd(&extra[id * 6 + 3], rx);
        atomicAdd(&extra[id * 6 + 4], ry); atomicAdd(&extra[id * 6 + 5], rz);
    }
}

__global__ __launch_bounds__(BLK) void pol_main(const float4* __restrict__ p4,
                                                const float4* __restrict__ q4,
                                                const int*    __restrict__ batch,
                                                float* __restrict__ ws) {
    __shared__ float sslot[NSLOT * 6];
    __shared__ float sqsum;

    const int t = threadIdx.x;
    const int b = blockIdx.x;                        // tile id
    float* extra = ws + EXTRA_OFF;

    if (t < NSLOT * 6) sslot[t] = 0.f;
    if (t == 0) sqsum = 0.f;
    __syncthreads();                                 // LDS-only; vmem queue empty

    // independent loads: split info + 4 data loads, all in flight together
    const int4 si = ((const int4*)(ws + SPLIT_OFF))[b];
    const int vi = b * (TILE_NODES / 4) + t;         // float4 group (4 nodes)
    float4 qv = q4[vi];
    float4 p0 = p4[3 * vi + 0];
    float4 p1 = p4[3 * vi + 1];
    float4 p2 = p4[3 * vi + 2];

    const int i0 = si.x, i1 = si.y, split = si.z;
    const bool general = (i1 > i0 + 1);              // >=3 graphs in tile: impossible here

    const int lane   = t & 63;
    const int wstart = b * TILE_NODES + (t >> 6) * 256;   // wave's first node

    float qs[4] = {qv.x, qv.y, qv.z, qv.w};
    float px[4] = {p0.x, p0.w, p1.z, p2.y};
    float py[4] = {p0.y, p1.x, p1.w, p2.z};
    float pz[4] = {p0.z, p1.y, p2.x, p2.w};
    float qsum = (qs[0] + qs[1]) + (qs[2] + qs[3]);

    if (!general) {
        const bool pure = (split <= wstart) || (split >= wstart + 256);
        if (pure) {
            float ax = 0, ay = 0, az = 0, rx = 0, ry = 0, rz = 0;
            #pragma unroll
            for (int k = 0; k < 4; ++k) {
                ax = fmaf(qs[k], px[k], ax); ay = fmaf(qs[k], py[k], ay);
                az = fmaf(qs[k], pz[k], az);
                rx += px[k]; ry += py[k]; rz += pz[k];
            }
            #pragma unroll
            for (int off = 32; off > 0; off >>= 1) {
                ax += __shfl_down(ax, off, 64); ay += __shfl_down(ay, off, 64);
                az += __shfl_down(az, off, 64); rx += __shfl_down(rx, off, 64);
                ry += __shfl_down(ry, off, 64); rz += __shfl_down(rz, off, 64);
            }
            if (lane == 0) {
                int id = (split <= wstart) ? i1 : i0;
                flush_seg(id, i0, ax, ay, az, rx, ry, rz, sslot, extra);
            }
        } else {  // wave straddles the split (<= 1 wave per tile boundary)
            float aqx = 0, aqy = 0, aqz = 0, arx = 0, ary = 0, arz = 0;
            float bqx = 0, bqy = 0, bqz = 0, brx = 0, bry = 0, brz = 0;
            const int n0 = vi * 4;                   // node index of element 0
            #pragma unroll
            for (int k = 0; k < 4; ++k) {
                if (n0 + k < split) {
                    aqx = fmaf(qs[k], px[k], aqx); aqy = fmaf(qs[k], py[k], aqy);
                    aqz = fmaf(qs[k], pz[k], aqz);
                    arx += px[k]; ary += py[k]; arz += pz[k];
                } else {
                    bqx = fmaf(qs[k], px[k], bqx); bqy = fmaf(qs[k], py[k], bqy);
                    bqz = fmaf(qs[k], pz[k], bqz);
                    brx += px[k]; bry += py[k]; brz += pz[k];
                }
            }
            #pragma unroll
            for (int off = 32; off > 0; off >>= 1) {
                aqx += __shfl_down(aqx, off, 64); aqy += __shfl_down(aqy, off, 64);
                aqz += __shfl_down(aqz, off, 64); arx += __shfl_down(arx, off, 64);
                ary += __shfl_down(ary, off, 64); arz += __shfl_down(arz, off, 64);
                bqx += __shfl_down(bqx, off, 64); bqy += __shfl_down(bqy, off, 64);
                bqz += __shfl_down(bqz, off, 64); brx += __shfl_down(brx, off, 64);
                bry += __shfl_down(bry, off, 64); brz += __shfl_down(brz, off, 64);
            }
            if (lane == 0) {
                flush_seg(i0, i0, aqx, aqy, aqz, arx, ary, arz, sslot, extra);
                flush_seg(i1, i0, bqx, bqy, bqz, brx, bry, brz, sslot, extra);
            }
        }
    } else {  // never for this input: per-node atomics, correct
        const int n0 = vi * 4;
        for (int k = 0; k < 4; ++k) {
            int id = batch[n0 + k];
            atomicAdd(&extra[id * 6 + 0], qs[k] * px[k]);
            atomicAdd(&extra[id * 6 + 1], qs[k] * py[k]);
            atomicAdd(&extra[id * 6 + 2], qs[k] * pz[k]);
            atomicAdd(&extra[id * 6 + 3], px[k]);
            atomicAdd(&extra[id * 6 + 4], py[k]);
            atomicAdd(&extra[id * 6 + 5], pz[k]);
        }
    }

    // tile qsum: wave butterfly + one LDS atomic per wave
    #pragma unroll
    for (int off = 32; off > 0; off >>= 1) qsum += __shfl_down(qsum, off, 64);
    if (lane == 0) atomicAdd(&sqsum, qsum);
    __syncthreads();

    float* rec = ws + REC_OFF + (size_t)b * REC_STRIDE;
    if (t == 0) rec[0] = sqsum;
    if (t < NSLOT * 6) rec[8 + t] = sslot[t];
}

// Single block, 1024 threads: mean from NT tile qsums, then per-graph gather
// via binary search over sorted tile base ids (rounds 3-7 proven logic).
__global__ __launch_bounds__(1024) void finalize_kernel(const float* __restrict__ ws,
                                                        float* __restrict__ out) {
    __shared__ float sm[16];
    __shared__ float smean;
    const int t = threadIdx.x;

    float s = 0.f;
    for (int i = t; i < NT; i += 1024) s += ws[REC_OFF + (size_t)i * REC_STRIDE];
    #pragma unroll
    for (int off = 32; off > 0; off >>= 1) s += __shfl_down(s, off, 64);
    if ((t & 63) == 0) sm[t >> 6] = s;
    __syncthreads();
    if (t == 0) {
        float tot = 0.f;
        #pragma unroll
        for (int i = 0; i < 16; ++i) tot += sm[i];
        smean = tot * (1.0f / (float)N_NODES);
    }
    __syncthreads();
    const float mean = smean;

    const int g = t;
    const int* ibase = (const int*)(ws + IBASE_OFF);
    const float* extra = ws + EXTRA_OFF;

    float qx = extra[g * 6 + 0], qy = extra[g * 6 + 1], qz = extra[g * 6 + 2];
    float rx = extra[g * 6 + 3], ry = extra[g * 6 + 4], rz = extra[g * 6 + 5];

    int lo = 0, hi = NT - 1, B = -1;
    while (lo <= hi) {
        int mid = (lo + hi) >> 1;
        if (ibase[mid] <= g) { B = mid; lo = mid + 1; } else hi = mid - 1;
    }
    for (int b = B; b >= 0; --b) {
        int sl = g - ibase[b];
        if (sl >= NSLOT) break;
        const float* p = ws + REC_OFF + (size_t)b * REC_STRIDE + 8 + sl * 6;
        qx += p[0]; qy += p[1]; qz += p[2];
        rx += p[3]; ry += p[4]; rz += p[5];
    }
    out[g * 3 + 0] = fmaf(-mean, rx, qx);
    out[g * 3 + 1] = fmaf(-mean, ry, qy);
    out[g * 3 + 2] = fmaf(-mean, rz, qz);
}

// ---------------- fallback path (round-1 code, known correct) ----------------

__global__ void sum_q_kernel(const float* __restrict__ q, float* __restrict__ ws, int n4) {
    int tid = blockIdx.x * blockDim.x + threadIdx.x;
    int stride = gridDim.x * blockDim.x;
    const float4* q4 = (const float4*)q;
    float s = 0.f;
    for (int i = tid; i < n4; i += stride) {
        float4 v = q4[i];
        s += (v.x + v.y) + (v.z + v.w);
    }
    for (int off = 32; off > 0; off >>= 1) s += __shfl_down(s, off, 64);
    __shared__ float smem[4];
    int lane = threadIdx.x & 63, wave = threadIdx.x >> 6;
    if (lane == 0) smem[wave] = s;
    __syncthreads();
    if (threadIdx.x == 0) atomicAdd(ws, (smem[0] + smem[1]) + (smem[2] + smem[3]));
}

__global__ void pol_atomic_kernel(const float* __restrict__ pos,
                                  const float* __restrict__ q,
                                  const int*   __restrict__ batch,
                                  const float* __restrict__ ws,
                                  float* __restrict__ out, int n) {
    const float mean = ws[0] * (1.0f / (float)N_NODES);
    int tid = blockIdx.x * blockDim.x + threadIdx.x;
    int stride = gridDim.x * blockDim.x;
    int n4 = n >> 2;
    const float4* q4 = (const float4*)q;
    const int4*   b4 = (const int4*)batch;
    const float4* p4 = (const float4*)pos;

    for (int i = tid; i < n4; i += stride) {
        float4 qv = q4[i];
        int4   bv = b4[i];
        float4 p0 = p4[3 * i + 0];
        float4 p1 = p4[3 * i + 1];
        float4 p2 = p4[3 * i + 2];
        float qs[4] = {qv.x - mean, qv.y - mean, qv.z - mean, qv.w - mean};
        int  ids[4] = {bv.x, bv.y, bv.z, bv.w};
        float px[4] = {p0.x, p0.w, p1.z, p2.y};
        float py[4] = {p0.y, p1.x, p1.w, p2.z};
        float pz[4] = {p0.z, p1.y, p2.x, p2.w};
        int cur = ids[0];
        float sx = 0.f, sy = 0.f, sz = 0.f;
        #pragma unroll
        for (int j = 0; j < 4; ++j) {
            if (ids[j] != cur) {
                atomicAdd(&out[cur * 3 + 0], sx);
                atomicAdd(&out[cur * 3 + 1], sy);
                atomicAdd(&out[cur * 3 + 2], sz);
                sx = sy = sz = 0.f;
                cur = ids[j];
            }
            sx = fmaf(qs[j], px[j], sx);
            sy = fmaf(qs[j], py[j], sy);
            sz = fmaf(qs[j], pz[j], sz);
        }
        int first = __shfl(cur, 0, 64);
        bool uniform = __all(cur == first);
        if (uniform) {
            for (int off = 32; off > 0; off >>= 1) {
                sx += __shfl_down(sx, off, 64);
                sy += __shfl_down(sy, off, 64);
                sz += __shfl_down(sz, off, 64);
            }
            if ((threadIdx.x & 63) == 0) {
                atomicAdd(&out[cur * 3 + 0], sx);
                atomicAdd(&out[cur * 3 + 1], sy);
                atomicAdd(&out[cur * 3 + 2], sz);
            }
        } else {
            atomicAdd(&out[cur * 3 + 0], sx);
            atomicAdd(&out[cur * 3 + 1], sy);
            atomicAdd(&out[cur * 3 + 2], sz);
        }
    }
}

extern "C" void kernel_launch(void* const* d_in, const int* in_sizes, int n_in,
                              void* d_out, int out_size, void* d_ws, size_t ws_size,
                              hipStream_t stream) {
    const float* pos   = (const float*)d_in[0];
    const float* q     = (const float*)d_in[1];
    const int*   batch = (const int*)d_in[2];
    float* out = (float*)d_out;
    float* ws  = (float*)d_ws;
    int n = in_sizes[1];

    if (ws_size >= (size_t)WS_FLOATS * sizeof(float)) {
        split_kernel<<<NT / BLK, BLK, 0, stream>>>(batch, ws);       // 32 blocks
        pol_main<<<NT, BLK, 0, stream>>>((const float4*)pos, (const float4*)q,
                                         batch, ws);                 // 8192 blocks
        finalize_kernel<<<1, 1024, 0, stream>>>(ws, out);
    } else {
        hipMemsetAsync(d_out, 0, (size_t)out_size * sizeof(float), stream);
        hipMemsetAsync(d_ws, 0, sizeof(float), stream);
        sum_q_kernel<<<4096, BLK, 0, stream>>>(q, ws, n >> 2);
        pol_atomic_kernel<<<8192, BLK, 0, stream>>>(pos, q, batch, ws, out, n);
    }
}

// Round 9
// 214.828 us; speedup vs baseline: 1.1369x; 1.1369x over previous
//
#include <hip/hip_runtime.h>

// pol[g] = sum_{i in g} (q_i - mean(q)) * r_i = (sum_g q r) - mean * (sum_g r)
// Round 9: wave-autonomous pol_main. Each WAVE owns a 1024-node tile; no LDS,
// no __syncthreads, no atomics anywhere in the hot kernel. Branchless A/B
// compare-select vs the tile's precomputed split, 7- or 13-value butterfly,
// lane0 plain-stores a 16-float record {qsum, i0, i1, A[6], B[6]}.
// split_kernel: per-tile {i0,i1,split} + zeroes extra[]. finalize: mean from
// 8192 qsums + per-graph gather over the ~9 touching tiles (binary search).

#define N_NODES     8388608
#define NUM_GRAPHS  1024
#define BLK         256
#define TILE_NODES  1024                             // per WAVE
#define NT          (N_NODES / TILE_NODES)           // 8192 wave-tiles
#define G4          (TILE_NODES / 4)                 // 256 float4 groups per tile

// ws layout (float offsets)
#define IBASE_OFF   16                               // int ibase[NT]
#define SPLIT_OFF   (IBASE_OFF + NT)                 // int4 split[NT]
#define REC_OFF     (SPLIT_OFF + 4 * NT)             // rec[NT][16]
#define REC_STRIDE  16
#define EXTRA_OFF   (REC_OFF + NT * REC_STRIDE)      // extra[NUM_GRAPHS][6]
#define WS_FLOATS   (EXTRA_OFF + NUM_GRAPHS * 6)     // 178192 floats = 713 KB

__global__ __launch_bounds__(BLK) void split_kernel(const int* __restrict__ batch,
                                                    float* __restrict__ ws) {
    int b = blockIdx.x * BLK + threadIdx.x;          // tile id, 0..NT-1
    if (b >= NT) return;
    if (b < 2048) {                                  // zero extra[]: 6144 floats
        float* extra = ws + EXTRA_OFF;
        extra[b * 3 + 0] = 0.f; extra[b * 3 + 1] = 0.f; extra[b * 3 + 2] = 0.f;
    }
    const int s = b * TILE_NODES;
    const int e = s + TILE_NODES;
    int i0 = batch[s];
    int i1 = batch[e - 1];
    int split = e;
    if (i1 != i0) {                                  // first idx in (s,e) with batch > i0
        int lo = s + 1, hi = e - 1;
        while (lo < hi) {
            int mid = (lo + hi) >> 1;
            if (batch[mid] > i0) hi = mid; else lo = mid + 1;
        }
        split = lo;
    }
    ((int4*)(ws + SPLIT_OFF))[b] = make_int4(i0, i1, split, 0);
    ((int*)(ws + IBASE_OFF))[b] = i0;
}

__global__ __launch_bounds__(BLK) void pol_main(const float4* __restrict__ p4,
                                                const float4* __restrict__ q4,
                                                const int*    __restrict__ batch,
                                                float* __restrict__ ws) {
    const int lane = threadIdx.x & 63;
    const int w    = blockIdx.x * 4 + (threadIdx.x >> 6);   // wave-tile id
    float* extra = ws + EXTRA_OFF;

    const int4 si = ((const int4*)(ws + SPLIT_OFF))[w];
    const int i0 = si.x, i1 = si.y, split = si.z;
    const bool general = (i1 > i0 + 1);              // >=3 graphs in 1024 nodes: impossible

    // 16 independent float4 loads (12 pos + 4 q), nothing else in the kernel
    const int vi0 = w * G4;
    float4 Q[4], P0[4], P1[4], P2[4];
    #pragma unroll
    for (int j = 0; j < 4; ++j) {
        int vi = vi0 + j * 64 + lane;
        Q[j]  = q4[vi];
        P0[j] = p4[3 * vi + 0];
        P1[j] = p4[3 * vi + 1];
        P2[j] = p4[3 * vi + 2];
    }

    float qsum = 0.f;
    float aqx = 0, aqy = 0, aqz = 0, arx = 0, ary = 0, arz = 0;
    float bqx = 0, bqy = 0, bqz = 0, brx = 0, bry = 0, brz = 0;

    if (!general) {
        #pragma unroll
        for (int j = 0; j < 4; ++j) {
            int n0 = (vi0 + j * 64 + lane) * 4;      // node index of element 0
            float qs[4] = {Q[j].x, Q[j].y, Q[j].z, Q[j].w};
            float px[4] = {P0[j].x, P0[j].w, P1[j].z, P2[j].y};
            float py[4] = {P0[j].y, P1[j].x, P1[j].w, P2[j].z};
            float pz[4] = {P0[j].z, P1[j].y, P2[j].x, P2[j].w};
            qsum += (qs[0] + qs[1]) + (qs[2] + qs[3]);
            #pragma unroll
            for (int k = 0; k < 4; ++k) {
                if (n0 + k < split) {                // pure tile: always true (split = e)
                    aqx = fmaf(qs[k], px[k], aqx); aqy = fmaf(qs[k], py[k], aqy);
                    aqz = fmaf(qs[k], pz[k], aqz);
                    arx += px[k]; ary += py[k]; arz += pz[k];
                } else {
                    bqx = fmaf(qs[k], px[k], bqx); bqy = fmaf(qs[k], py[k], bqy);
                    bqz = fmaf(qs[k], pz[k], bqz);
                    brx += px[k]; bry += py[k]; brz += pz[k];
                }
            }
        }
    } else {  // never for this input: per-node atomics into extra[], correct
        #pragma unroll
        for (int j = 0; j < 4; ++j) {
            int n0 = (vi0 + j * 64 + lane) * 4;
            float qs[4] = {Q[j].x, Q[j].y, Q[j].z, Q[j].w};
            float px[4] = {P0[j].x, P0[j].w, P1[j].z, P2[j].y};
            float py[4] = {P0[j].y, P1[j].x, P1[j].w, P2[j].z};
            float pz[4] = {P0[j].z, P1[j].y, P2[j].x, P2[j].w};
            for (int k = 0; k < 4; ++k) {
                int id = batch[n0 + k];
                qsum += qs[k];
                atomicAdd(&extra[id * 6 + 0], qs[k] * px[k]);
                atomicAdd(&extra[id * 6 + 1], qs[k] * py[k]);
                atomicAdd(&extra[id * 6 + 2], qs[k] * pz[k]);
                atomicAdd(&extra[id * 6 + 3], px[k]);
                atomicAdd(&extra[id * 6 + 4], py[k]);
                atomicAdd(&extra[id * 6 + 5], pz[k]);
            }
        }
    }

    // qsum + A butterfly (7 values), B only if mixed (wave-uniform branch)
    #pragma unroll
    for (int off = 32; off > 0; off >>= 1) {
        qsum += __shfl_down(qsum, off, 64);
        aqx += __shfl_down(aqx, off, 64); aqy += __shfl_down(aqy, off, 64);
        aqz += __shfl_down(aqz, off, 64); arx += __shfl_down(arx, off, 64);
        ary += __shfl_down(ary, off, 64); arz += __shfl_down(arz, off, 64);
    }
    if (i1 != i0 && !general) {
        #pragma unroll
        for (int off = 32; off > 0; off >>= 1) {
            bqx += __shfl_down(bqx, off, 64); bqy += __shfl_down(bqy, off, 64);
            bqz += __shfl_down(bqz, off, 64); brx += __shfl_down(brx, off, 64);
            bry += __shfl_down(bry, off, 64); brz += __shfl_down(brz, off, 64);
        }
    }

    if (lane == 0) {                                 // plain stores, no coupling
        float* rec = ws + REC_OFF + (size_t)w * REC_STRIDE;
        rec[0] = qsum;
        rec[4] = aqx; rec[5] = aqy; rec[6] = aqz;
        rec[7] = arx; rec[8] = ary; rec[9] = arz;
        rec[10] = bqx; rec[11] = bqy; rec[12] = bqz;
        rec[13] = brx; rec[14] = bry; rec[15] = brz;
    }
}

// Single block, 1024 threads: mean from NT wave qsums, then per-graph gather:
// walk tiles touching g (i0<=g<=i1), add A if i0==g, B if i1==g (mixed).
__global__ __launch_bounds__(1024) void finalize_kernel(const float* __restrict__ ws,
                                                        float* __restrict__ out) {
    __shared__ float sm[16];
    __shared__ float smean;
    const int t = threadIdx.x;

    float s = 0.f;
    for (int i = t; i < NT; i += 1024) s += ws[REC_OFF + (size_t)i * REC_STRIDE];
    #pragma unroll
    for (int off = 32; off > 0; off >>= 1) s += __shfl_down(s, off, 64);
    if ((t & 63) == 0) sm[t >> 6] = s;
    __syncthreads();
    if (t == 0) {
        float tot = 0.f;
        #pragma unroll
        for (int i = 0; i < 16; ++i) tot += sm[i];
        smean = tot * (1.0f / (float)N_NODES);
    }
    __syncthreads();
    const float mean = smean;

    const int g = t;
    const int* ibase = (const int*)(ws + IBASE_OFF);
    const int4* sp4  = (const int4*)(ws + SPLIT_OFF);
    const float* extra = ws + EXTRA_OFF;

    float qx = extra[g * 6 + 0], qy = extra[g * 6 + 1], qz = extra[g * 6 + 2];
    float rx = extra[g * 6 + 3], ry = extra[g * 6 + 4], rz = extra[g * 6 + 5];

    // last tile with i0 <= g
    int lo = 0, hi = NT - 1, B = -1;
    while (lo <= hi) {
        int mid = (lo + hi) >> 1;
        if (ibase[mid] <= g) { B = mid; lo = mid + 1; } else hi = mid - 1;
    }
    for (int b = B; b >= 0; --b) {
        int4 sb = sp4[b];
        if (sb.y < g) break;                         // tiles further left end before g
        const float* r = ws + REC_OFF + (size_t)b * REC_STRIDE;
        if (sb.x == g) {
            qx += r[4]; qy += r[5]; qz += r[6];
            rx += r[7]; ry += r[8]; rz += r[9];
        }
        if (sb.y == g && sb.y != sb.x) {
            qx += r[10]; qy += r[11]; qz += r[12];
            rx += r[13]; ry += r[14]; rz += r[15];
        }
    }
    out[g * 3 + 0] = fmaf(-mean, rx, qx);
    out[g * 3 + 1] = fmaf(-mean, ry, qy);
    out[g * 3 + 2] = fmaf(-mean, rz, qz);
}

// ---------------- fallback path (round-1 code, known correct) ----------------

__global__ void sum_q_kernel(const float* __restrict__ q, float* __restrict__ ws, int n4) {
    int tid = blockIdx.x * blockDim.x + threadIdx.x;
    int stride = gridDim.x * blockDim.x;
    const float4* q4 = (const float4*)q;
    float s = 0.f;
    for (int i = tid; i < n4; i += stride) {
        float4 v = q4[i];
        s += (v.x + v.y) + (v.z + v.w);
    }
    for (int off = 32; off > 0; off >>= 1) s += __shfl_down(s, off, 64);
    __shared__ float smem[4];
    int lane = threadIdx.x & 63, wave = threadIdx.x >> 6;
    if (lane == 0) smem[wave] = s;
    __syncthreads();
    if (threadIdx.x == 0) atomicAdd(ws, (smem[0] + smem[1]) + (smem[2] + smem[3]));
}

__global__ void pol_atomic_kernel(const float* __restrict__ pos,
                                  const float* __restrict__ q,
                                  const int*   __restrict__ batch,
                                  const float* __restrict__ ws,
                                  float* __restrict__ out, int n) {
    const float mean = ws[0] * (1.0f / (float)N_NODES);
    int tid = blockIdx.x * blockDim.x + threadIdx.x;
    int stride = gridDim.x * blockDim.x;
    int n4 = n >> 2;
    const float4* q4 = (const float4*)q;
    const int4*   b4 = (const int4*)batch;
    const float4* p4 = (const float4*)pos;

    for (int i = tid; i < n4; i += stride) {
        float4 qv = q4[i];
        int4   bv = b4[i];
        float4 p0 = p4[3 * i + 0];
        float4 p1 = p4[3 * i + 1];
        float4 p2 = p4[3 * i + 2];
        float qs[4] = {qv.x - mean, qv.y - mean, qv.z - mean, qv.w - mean};
        int  ids[4] = {bv.x, bv.y, bv.z, bv.w};
        float px[4] = {p0.x, p0.w, p1.z, p2.y};
        float py[4] = {p0.y, p1.x, p1.w, p2.z};
        float pz[4] = {p0.z, p1.y, p2.x, p2.w};
        int cur = ids[0];
        float sx = 0.f, sy = 0.f, sz = 0.f;
        #pragma unroll
        for (int j = 0; j < 4; ++j) {
            if (ids[j] != cur) {
                atomicAdd(&out[cur * 3 + 0], sx);
                atomicAdd(&out[cur * 3 + 1], sy);
                atomicAdd(&out[cur * 3 + 2], sz);
                sx = sy = sz = 0.f;
                cur = ids[j];
            }
            sx = fmaf(qs[j], px[j], sx);
            sy = fmaf(qs[j], py[j], sy);
            sz = fmaf(qs[j], pz[j], sz);
        }
        int first = __shfl(cur, 0, 64);
        bool uniform = __all(cur == first);
        if (uniform) {
            for (int off = 32; off > 0; off >>= 1) {
                sx += __shfl_down(sx, off, 64);
                sy += __shfl_down(sy, off, 64);
                sz += __shfl_down(sz, off, 64);
            }
            if ((threadIdx.x & 63) == 0) {
                atomicAdd(&out[cur * 3 + 0], sx);
                atomicAdd(&out[cur * 3 + 1], sy);
                atomicAdd(&out[cur * 3 + 2], sz);
            }
        } else {
            atomicAdd(&out[cur * 3 + 0], sx);
            atomicAdd(&out[cur * 3 + 1], sy);
            atomicAdd(&out[cur * 3 + 2], sz);
        }
    }
}

extern "C" void kernel_launch(void* const* d_in, const int* in_sizes, int n_in,
                              void* d_out, int out_size, void* d_ws, size_t ws_size,
                              hipStream_t stream) {
    const float* pos   = (const float*)d_in[0];
    const float* q     = (const float*)d_in[1];
    const int*   batch = (const int*)d_in[2];
    float* out = (float*)d_out;
    float* ws  = (float*)d_ws;
    int n = in_sizes[1];

    if (ws_size >= (size_t)WS_FLOATS * sizeof(float)) {
        split_kernel<<<NT / BLK, BLK, 0, stream>>>(batch, ws);       // 32 blocks
        pol_main<<<NT / 4, BLK, 0, stream>>>((const float4*)pos, (const float4*)q,
                                             batch, ws);             // 2048 blocks, 4 waves
        finalize_kernel<<<1, 1024, 0, stream>>>(ws, out);
    } else {
        hipMemsetAsync(d_out, 0, (size_t)out_size * sizeof(float), stream);
        hipMemsetAsync(d_ws, 0, sizeof(float), stream);
        sum_q_kernel<<<4096, BLK, 0, stream>>>(q, ws, n >> 2);
        pol_atomic_kernel<<<8192, BLK, 0, stream>>>(pos, q, batch, ws, out, n);
    }
}